// Round 1
// baseline (680.918 us; speedup 1.0000x reference)
//
#include <hip/hip_runtime.h>
#include <hip/hip_bf16.h>
#include <stdint.h>

typedef __bf16 bf16_t;
typedef __bf16 bf16x8 __attribute__((ext_vector_type(8)));
typedef __bf16 bf16x4 __attribute__((ext_vector_type(4)));
typedef float f32x4 __attribute__((ext_vector_type(4)));

// async global->LDS, 16B per lane. LDS dest must be wave-uniform base + lane*16.
__device__ __forceinline__ void gload_lds16(const bf16_t* g, bf16_t* l) {
  __builtin_amdgcn_global_load_lds((const __attribute__((address_space(1))) void*)g,
                                   (__attribute__((address_space(3))) void*)l, 16, 0, 0);
}

// ---------------- fp32 W[k][m] -> bf16 Bt[m][k] (tiled transpose + cast) --------
__global__ __launch_bounds__(256) void transpose_cast_k(const float* __restrict__ W,
                                                        bf16_t* __restrict__ Bt,
                                                        int KDin, int MDin) {
  __shared__ float tile[64][65];
  const int bm = blockIdx.x, bk = blockIdx.y;
  const int c = threadIdx.x & 63, r0 = threadIdx.x >> 6;
#pragma unroll
  for (int rr = 0; rr < 16; ++rr) {
    int row = rr * 4 + r0;
    tile[row][c] = W[(size_t)(bk * 64 + row) * MDin + bm * 64 + c];
  }
  __syncthreads();
#pragma unroll
  for (int rr = 0; rr < 16; ++rr) {
    int mo = rr * 4 + r0;
    Bt[(size_t)(bm * 64 + mo) * KDin + bk * 64 + c] = (bf16_t)tile[c][mo];
  }
}

// ---------------- feat[order[j]] -> bf16 featp[j] ------------------------------
__global__ __launch_bounds__(256) void gather_cast_k(const float* __restrict__ feat,
                                                     const int* __restrict__ order,
                                                     bf16_t* __restrict__ featp) {
  const int id = blockIdx.x * 256 + threadIdx.x;  // 32768*192 total
  const int j = id / 192;
  const int c = (id % 192) * 4;
  const int g = order[j];
  const float4 v = *(const float4*)(feat + (size_t)g * 768 + c);
  bf16x4 o;
  o[0] = (bf16_t)v.x; o[1] = (bf16_t)v.y; o[2] = (bf16_t)v.z; o[3] = (bf16_t)v.w;
  *(bf16x4*)(featp + (size_t)j * 768 + c) = o;
}

// ---------------- GEMM: C[j][m] = A[j][:] . Bt[m][:] + bias[m] -----------------
// A [NR][768] bf16, Bt [MD][768] bf16. 128x128 tile, BK=32, 4 waves (2x2 of 64x64).
// MODE 0: bf16 store to Cb[j][MD].  MODE 1: fp32 scatter Cf[order[j]][768].
template <int MODE>
__global__ __launch_bounds__(256) void gemm_bt_k(const bf16_t* __restrict__ A,
                                                 const bf16_t* __restrict__ Bt,
                                                 const float* __restrict__ bias,
                                                 bf16_t* __restrict__ Cb,
                                                 float* __restrict__ Cf,
                                                 const int* __restrict__ order,
                                                 int MD) {
  __shared__ bf16_t As[128 * 32];
  __shared__ bf16_t Bs[128 * 32];
  const int tid = threadIdx.x;
  const int lane = tid & 63;
  const int wave = tid >> 6;
  const int wr = wave >> 1, wc = wave & 1;
  const int lq = lane & 15, lk = lane >> 4;
  const int bx = blockIdx.x, by = blockIdx.y;

  const bf16_t* gA = A + (size_t)(by * 128 + (tid >> 2)) * 768 + (tid & 3) * 8;
  const bf16_t* gB = Bt + (size_t)(bx * 128 + (tid >> 2)) * 768 + (tid & 3) * 8;
  bf16_t* lA = As + tid * 8;
  bf16_t* lB = Bs + tid * 8;

  f32x4 acc[4][4] = {};

  for (int kk = 0; kk < 24; ++kk) {
    gload_lds16(gA, lA);
    gload_lds16(gA + 64 * 768, lA + 2048);
    gload_lds16(gB, lB);
    gload_lds16(gB + 64 * 768, lB + 2048);
    gA += 32;
    gB += 32;
    __syncthreads();
    bf16x8 af[4], bfr[4];
#pragma unroll
    for (int t = 0; t < 4; ++t) {
      af[t]  = *(const bf16x8*)(As + (wr * 64 + t * 16 + lq) * 32 + lk * 8);
      bfr[t] = *(const bf16x8*)(Bs + (wc * 64 + t * 16 + lq) * 32 + lk * 8);
    }
#pragma unroll
    for (int mt = 0; mt < 4; ++mt)
#pragma unroll
      for (int nt = 0; nt < 4; ++nt)
        acc[mt][nt] = __builtin_amdgcn_mfma_f32_16x16x32_bf16(af[mt], bfr[nt], acc[mt][nt], 0, 0, 0);
    __syncthreads();
  }

  const int colb = bx * 128 + wc * 64;
  float bcol[4];
#pragma unroll
  for (int nt = 0; nt < 4; ++nt) bcol[nt] = bias[colb + nt * 16 + lq];

#pragma unroll
  for (int mt = 0; mt < 4; ++mt) {
    const int row = by * 128 + wr * 64 + mt * 16 + lk * 4;
    if (MODE == 0) {
#pragma unroll
      for (int nt = 0; nt < 4; ++nt) {
        const int col = colb + nt * 16 + lq;
#pragma unroll
        for (int r = 0; r < 4; ++r)
          Cb[(size_t)(row + r) * MD + col] = (bf16_t)(acc[mt][nt][r] + bcol[nt]);
      }
    } else {
      int ro[4];
#pragma unroll
      for (int r = 0; r < 4; ++r) ro[r] = order[row + r];
#pragma unroll
      for (int nt = 0; nt < 4; ++nt) {
        const int col = colb + nt * 16 + lq;
#pragma unroll
        for (int r = 0; r < 4; ++r)
          Cf[(size_t)ro[r] * 768 + col] = acc[mt][nt][r] + bcol[nt];
      }
    }
  }
}

// ---------------- RoPE3D in-place on q,k + V transpose into Vt -----------------
// qkv [32768][2304] bf16 (rows already permuted).  Vt [(p*8+h)*96 + d][256].
__global__ __launch_bounds__(256) void rope_pack_k(bf16_t* __restrict__ qkv,
                                                   bf16_t* __restrict__ Vt,
                                                   const int* __restrict__ grid_coord,
                                                   const int* __restrict__ order) {
  const int h = blockIdx.x, p = blockIdx.y;
  const int t = threadIdx.x;
  const int j = p * 256 + t;
  const int g = order[j];
  float pos[3];
  pos[0] = (float)grid_coord[g * 3 + 0];
  pos[1] = (float)grid_coord[g * 3 + 1];
  pos[2] = (float)grid_coord[g * 3 + 2];
  bf16_t* row = qkv + (size_t)j * 2304 + h * 96;
  const float NEGL = -0.41524101186f;  // -log2(100)/16
#pragma unroll
  for (int a = 0; a < 3; ++a) {
    const float pa = pos[a];
    bf16x8 q0 = *(bf16x8*)(row + a * 32);
    bf16x8 q1 = *(bf16x8*)(row + a * 32 + 8);
    bf16x8 q2 = *(bf16x8*)(row + a * 32 + 16);
    bf16x8 q3 = *(bf16x8*)(row + a * 32 + 24);
    bf16x8 k0 = *(bf16x8*)(row + 768 + a * 32);
    bf16x8 k1 = *(bf16x8*)(row + 768 + a * 32 + 8);
    bf16x8 k2 = *(bf16x8*)(row + 768 + a * 32 + 16);
    bf16x8 k3 = *(bf16x8*)(row + 768 + a * 32 + 24);
    float s[16], c[16];
#pragma unroll
    for (int i = 0; i < 16; ++i) {
      float ang = pa * exp2f(NEGL * (float)i);
      __sincosf(ang, &s[i], &c[i]);
    }
#pragma unroll
    for (int i = 0; i < 8; ++i) {
      float x1 = (float)q0[i], x2 = (float)q2[i];
      q0[i] = (bf16_t)(x1 * c[i] - x2 * s[i]);
      q2[i] = (bf16_t)(x1 * s[i] + x2 * c[i]);
      float y1 = (float)q1[i], y2 = (float)q3[i];
      q1[i] = (bf16_t)(y1 * c[i + 8] - y2 * s[i + 8]);
      q3[i] = (bf16_t)(y1 * s[i + 8] + y2 * c[i + 8]);
      float u1 = (float)k0[i], u2 = (float)k2[i];
      k0[i] = (bf16_t)(u1 * c[i] - u2 * s[i]);
      k2[i] = (bf16_t)(u1 * s[i] + u2 * c[i]);
      float w1 = (float)k1[i], w2 = (float)k3[i];
      k1[i] = (bf16_t)(w1 * c[i + 8] - w2 * s[i + 8]);
      k3[i] = (bf16_t)(w1 * s[i + 8] + w2 * c[i + 8]);
    }
    *(bf16x8*)(row + a * 32) = q0;
    *(bf16x8*)(row + a * 32 + 8) = q1;
    *(bf16x8*)(row + a * 32 + 16) = q2;
    *(bf16x8*)(row + a * 32 + 24) = q3;
    *(bf16x8*)(row + 768 + a * 32) = k0;
    *(bf16x8*)(row + 768 + a * 32 + 8) = k1;
    *(bf16x8*)(row + 768 + a * 32 + 16) = k2;
    *(bf16x8*)(row + 768 + a * 32 + 24) = k3;
  }
  // V transpose: Vt[(p*8+h)*96 + d][t] = v[t][d]; lanes = consecutive t -> coalesced.
  bf16_t* vt = Vt + (size_t)(p * 8 + h) * 96 * 256 + t;
  const bf16_t* vrow = row + 1536;
#pragma unroll
  for (int d0 = 0; d0 < 96; d0 += 8) {
    bf16x8 v = *(const bf16x8*)(vrow + d0);
#pragma unroll
    for (int i = 0; i < 8; ++i) vt[(d0 + i) * 256] = v[i];
  }
}

// ---------------- windowed attention ------------------------------------------
// grid = P*H*4; block = 4 waves x 16 q-rows = 64 q-rows of one (p,h).
// S = Q.K^T (MFMA, K frags streamed from global), softmax in C/D layout,
// P -> LDS (padded stride 264) -> A-layout frags, O = P.V (V frags from Vt).
__global__ __launch_bounds__(256) void attn_k(const bf16_t* __restrict__ qkv,
                                              const bf16_t* __restrict__ Vt,
                                              bf16_t* __restrict__ O) {
  __shared__ bf16_t P[4][16 * 264];  // per-wave 16x256 P, +8 pad (33792 B total)
  const int bid = blockIdx.x;
  const int chunk = bid & 3;
  const int ph = bid >> 2;
  const int h = ph & 7, p = ph >> 3;
  const int tid = threadIdx.x, lane = tid & 63, wave = tid >> 6;
  const int lq = lane & 15, lk = lane >> 4;
  const int tok0 = p * 256;
  const int qr0 = chunk * 64 + wave * 16;

  bf16x8 aq[3];
  {
    const bf16_t* qb = qkv + (size_t)(tok0 + qr0 + lq) * 2304 + h * 96 + lk * 8;
#pragma unroll
    for (int kc = 0; kc < 3; ++kc) aq[kc] = *(const bf16x8*)(qb + kc * 32);
  }

  f32x4 sacc[16];
  const bf16_t* kb0 = qkv + (size_t)(tok0 + lq) * 2304 + 768 + h * 96 + lk * 8;
#pragma unroll
  for (int nt = 0; nt < 16; ++nt) {
    f32x4 acc = {0.f, 0.f, 0.f, 0.f};
    const bf16_t* kb = kb0 + (size_t)nt * 16 * 2304;
#pragma unroll
    for (int kc = 0; kc < 3; ++kc) {
      bf16x8 bk = *(const bf16x8*)(kb + kc * 32);
      acc = __builtin_amdgcn_mfma_f32_16x16x32_bf16(aq[kc], bk, acc, 0, 0, 0);
    }
    sacc[nt] = acc;
  }

  const float scale = 0.10206207262f;  // 96^-0.5
  float linv[4];
#pragma unroll
  for (int r = 0; r < 4; ++r) {
    float m = -1e30f;
#pragma unroll
    for (int nt = 0; nt < 16; ++nt) m = fmaxf(m, sacc[nt][r]);
    m = fmaxf(m, __shfl_xor(m, 1));
    m = fmaxf(m, __shfl_xor(m, 2));
    m = fmaxf(m, __shfl_xor(m, 4));
    m = fmaxf(m, __shfl_xor(m, 8));
    m *= scale;
    float l = 0.f;
#pragma unroll
    for (int nt = 0; nt < 16; ++nt) {
      float e = __expf(sacc[nt][r] * scale - m);
      sacc[nt][r] = e;
      l += e;
    }
    l += __shfl_xor(l, 1);
    l += __shfl_xor(l, 2);
    l += __shfl_xor(l, 4);
    l += __shfl_xor(l, 8);
    linv[r] = 1.f / l;
  }

  bf16_t* pw = &P[wave][0];
#pragma unroll
  for (int nt = 0; nt < 16; ++nt)
#pragma unroll
    for (int r = 0; r < 4; ++r)
      pw[(lk * 4 + r) * 264 + nt * 16 + lq] = (bf16_t)sacc[nt][r];

  const bf16_t* vb0 = Vt + ((size_t)ph * 96 + lq) * 256 + lk * 8;
#pragma unroll
  for (int dt = 0; dt < 6; ++dt) {
    f32x4 oacc = {0.f, 0.f, 0.f, 0.f};
#pragma unroll
    for (int kc = 0; kc < 8; ++kc) {
      bf16x8 ap = *(const bf16x8*)(pw + lq * 264 + kc * 32 + lk * 8);
      bf16x8 vb = *(const bf16x8*)(vb0 + dt * 16 * 256 + kc * 32);
      oacc = __builtin_amdgcn_mfma_f32_16x16x32_bf16(ap, vb, oacc, 0, 0, 0);
    }
#pragma unroll
    for (int r = 0; r < 4; ++r) {
      const int trow = tok0 + qr0 + lk * 4 + r;
      O[(size_t)trow * 768 + h * 96 + dt * 16 + lq] = (bf16_t)(oacc[r] * linv[r]);
    }
  }
}

extern "C" void kernel_launch(void* const* d_in, const int* in_sizes, int n_in,
                              void* d_out, int out_size, void* d_ws, size_t ws_size,
                              hipStream_t stream) {
  const float* feat       = (const float*)d_in[0];
  const int*   grid_coord = (const int*)d_in[1];
  const int*   order      = (const int*)d_in[2];
  // d_in[3] = inverse (unused: scatter-by-order is equivalent)
  const float* w_qkv      = (const float*)d_in[4];
  const float* b_qkv      = (const float*)d_in[5];
  const float* w_proj     = (const float*)d_in[6];
  const float* b_proj     = (const float*)d_in[7];
  float* out = (float*)d_out;

  char* ws = (char*)d_ws;
  bf16_t* Bt1     = (bf16_t*)(ws);                 // 2304x768  bf16 (3,538,944 B)
  bf16_t* Bt2     = (bf16_t*)(ws + 3538944);       // 768x768   bf16 (1,179,648 B)
  bf16_t* featp   = (bf16_t*)(ws + 4718592);       // 32768x768 bf16 (50,331,648 B)
  bf16_t* qkv     = (bf16_t*)(ws + 55050240);      // 32768x2304 bf16 (150,994,944 B)
  bf16_t* Vt      = (bf16_t*)(ws + 206045184);     // 1024x96x256 bf16 (50,331,648 B)
  bf16_t* attnout = featp;                         // featp dead after gemm1; reuse

  transpose_cast_k<<<dim3(36, 12), 256, 0, stream>>>(w_qkv, Bt1, 768, 2304);
  transpose_cast_k<<<dim3(12, 12), 256, 0, stream>>>(w_proj, Bt2, 768, 768);
  gather_cast_k<<<24576, 256, 0, stream>>>(feat, order, featp);
  gemm_bt_k<0><<<dim3(18, 256), 256, 0, stream>>>(featp, Bt1, b_qkv, qkv, nullptr, nullptr, 2304);
  rope_pack_k<<<dim3(8, 128), 256, 0, stream>>>(qkv, Vt, grid_coord, order);
  attn_k<<<4096, 256, 0, stream>>>(qkv, Vt, attnout);
  gemm_bt_k<1><<<dim3(6, 256), 256, 0, stream>>>(attnout, Bt2, b_proj, nullptr, out, order, 768);
}